// Round 1
// baseline (1203.947 us; speedup 1.0000x reference)
//
#include <hip/hip_runtime.h>
#include <math.h>

#define NND 50000
#define NED 500000
#define FDIM 128
#define NREL 8

#define BM 64
#define BK 64
#define LDA 68   // padded LDS stride (f32): 68%32=4 -> <=2-way conflicts with x16-strided thread map

// ---------------- K1: per-node attention dots ----------------
__global__ void node_dots_kernel(const float* __restrict__ x,
                                 const float* __restrict__ wa,
                                 float* __restrict__ a_src,
                                 float* __restrict__ a_tgt) {
    int gid  = blockIdx.x * blockDim.x + threadIdx.x;
    int node = gid >> 6;          // one wave (64 lanes) per node
    int lane = threadIdx.x & 63;
    if (node >= NND) return;
    float2 v = *(const float2*)(x + (size_t)node * FDIM + lane * 2);
    float s1 = v.x * wa[2 * lane]        + v.y * wa[2 * lane + 1];
    float s2 = v.x * wa[FDIM + 2 * lane] + v.y * wa[FDIM + 2 * lane + 1];
#pragma unroll
    for (int off = 32; off > 0; off >>= 1) {
        s1 += __shfl_xor(s1, off);
        s2 += __shfl_xor(s2, off);
    }
    if (lane == 0) { a_src[node] = s1; a_tgt[node] = s2; }
}

// ---------------- K2: edge scatter (atomics) ----------------
__global__ void edge_scatter_kernel(const int* __restrict__ ei,
                                    const int* __restrict__ et,
                                    const float* __restrict__ x,
                                    const float* __restrict__ a_src,
                                    const float* __restrict__ a_tgt,
                                    const float* __restrict__ ba,
                                    float* __restrict__ agg,
                                    float* __restrict__ asum,
                                    int rel_lo, int rel_hi, int r_eff) {
    int gid  = blockIdx.x * blockDim.x + threadIdx.x;
    int e    = gid >> 5;          // 32 lanes per edge
    int lane = threadIdx.x & 31;
    if (e >= NED) return;
    int rel = et[e];
    if (rel < rel_lo || rel >= rel_hi) return;
    int src = ei[e];
    int tgt = ei[NED + e];
    float s = a_src[src] + a_tgt[tgt] + ba[0];
    float a = 1.0f / (1.0f + __expf(-s));
    float4 v = *(const float4*)(x + (size_t)src * FDIM + lane * 4);
    size_t seg = (size_t)tgt * r_eff + (rel - rel_lo);
    float* dst = agg + seg * FDIM + lane * 4;
    atomicAdd(dst + 0, a * v.x);
    atomicAdd(dst + 1, a * v.y);
    atomicAdd(dst + 2, a * v.z);
    atomicAdd(dst + 3, a * v.w);
    if (lane == 0) atomicAdd(asum + seg, a);
}

// ---------------- K3: fused output GEMM ----------------
// out[n,o] (+)= [self: bs[o] + sum_k x[n,k]Ws[o,k]]
//             + sum_{r<r_eff} ( sum_i agg[n,r,i]Wr[rel][o,i] + asum[n,r]*br[rel][o] )
__global__ __launch_bounds__(256) void final_gemm_kernel(
        const float* __restrict__ x,
        const float* __restrict__ Ws,
        const float* __restrict__ bs,
        const float* __restrict__ agg,
        const float* __restrict__ asum,
        const float* __restrict__ Wr,     // already offset to first relation of this pass
        const float* __restrict__ br,     // already offset likewise
        float* __restrict__ out,
        int r_eff, int include_self, int accumulate) {
    __shared__ float As[BM * LDA];     // 64 x 68
    __shared__ float Bs[FDIM * LDA];   // 128 x 68
    int tid  = threadIdx.x;
    int brow = blockIdx.x * BM;
    int tr = tid >> 4;     // 0..15 (row group)
    int tc = tid & 15;     // 0..15 (col group)

    float acc[4][8];
#pragma unroll
    for (int i = 0; i < 4; ++i)
#pragma unroll
        for (int j = 0; j < 8; ++j) acc[i][j] = 0.f;

    int nchunks = 2 * (include_self + r_eff);
    int arow = tid >> 2;   // 0..63, A staging row
    int af4  = tid & 3;
    int grow = brow + arow;
    int borow = tid >> 1;  // 0..127, B staging row
    int bf4  = tid & 1;

    for (int c = 0; c < nchunks; ++c) {
        int phase = c >> 1;
        int hlf   = c & 1;
        bool isSelf = (include_self && phase == 0);
        int rel = phase - include_self;
        const float* asrc;
        const float* bsrc;
        if (isSelf) {
            asrc = x + (size_t)grow * FDIM + hlf * BK;
            bsrc = Ws + (size_t)borow * FDIM + hlf * BK;
        } else {
            asrc = agg + ((size_t)grow * r_eff + rel) * FDIM + hlf * BK;
            bsrc = Wr + (size_t)rel * FDIM * FDIM + (size_t)borow * FDIM + hlf * BK;
        }
#pragma unroll
        for (int q = 0; q < 4; ++q) {
            int f4 = af4 + 4 * q;
            float4 v = make_float4(0.f, 0.f, 0.f, 0.f);
            if (grow < NND) v = *(const float4*)(asrc + f4 * 4);
            *(float4*)&As[arow * LDA + f4 * 4] = v;
        }
#pragma unroll
        for (int q = 0; q < 8; ++q) {
            int f4 = bf4 + 2 * q;
            *(float4*)&Bs[borow * LDA + f4 * 4] = *(const float4*)(bsrc + f4 * 4);
        }
        __syncthreads();
#pragma unroll 2
        for (int kk = 0; kk < BK; kk += 4) {
            float4 av[4];
            float4 bv[8];
#pragma unroll
            for (int i = 0; i < 4; ++i)
                av[i] = *(const float4*)&As[(i * 16 + tr) * LDA + kk];
#pragma unroll
            for (int j = 0; j < 8; ++j)
                bv[j] = *(const float4*)&Bs[(j * 16 + tc) * LDA + kk];
#pragma unroll
            for (int i = 0; i < 4; ++i)
#pragma unroll
                for (int j = 0; j < 8; ++j) {
                    acc[i][j] += av[i].x * bv[j].x;
                    acc[i][j] += av[i].y * bv[j].y;
                    acc[i][j] += av[i].z * bv[j].z;
                    acc[i][j] += av[i].w * bv[j].w;
                }
        }
        __syncthreads();
    }

    // asum @ br tail (K = r_eff)
    if (r_eff > 0) {
#pragma unroll
        for (int i = 0; i < 4; ++i) {
            int n = brow + i * 16 + tr;
            if (n >= NND) continue;
            for (int r = 0; r < r_eff; ++r) {
                float av = asum[(size_t)n * r_eff + r];
#pragma unroll
                for (int j = 0; j < 8; ++j)
                    acc[i][j] += av * br[(size_t)r * FDIM + j * 16 + tc];
            }
        }
    }
    if (include_self) {
#pragma unroll
        for (int j = 0; j < 8; ++j) {
            float b = bs[j * 16 + tc];
#pragma unroll
            for (int i = 0; i < 4; ++i) acc[i][j] += b;
        }
    }
#pragma unroll
    for (int i = 0; i < 4; ++i) {
        int n = brow + i * 16 + tr;
        if (n >= NND) continue;
#pragma unroll
        for (int j = 0; j < 8; ++j) {
            size_t idx = (size_t)n * FDIM + j * 16 + tc;
            if (accumulate) out[idx] += acc[i][j];
            else            out[idx] = acc[i][j];
        }
    }
}

extern "C" void kernel_launch(void* const* d_in, const int* in_sizes, int n_in,
                              void* d_out, int out_size, void* d_ws, size_t ws_size,
                              hipStream_t stream) {
    const float* x  = (const float*)d_in[0];
    const int*   ei = (const int*)d_in[1];
    const int*   et = (const int*)d_in[2];
    const float* Wr = (const float*)d_in[3];
    const float* br = (const float*)d_in[4];
    const float* Ws = (const float*)d_in[5];
    const float* bs = (const float*)d_in[6];
    const float* wa = (const float*)d_in[7];
    const float* ba = (const float*)d_in[8];
    float* out = (float*)d_out;
    float* ws  = (float*)d_ws;

    const size_t aggN = (size_t)NND * NREL * FDIM;            // 51.2M floats
    const size_t need_primary  = (aggN + (size_t)NND * NREL + 2 * (size_t)NND) * sizeof(float);
    const size_t yN = (size_t)NND * FDIM;                     // 6.4M floats
    const size_t need_fallback = (yN + 3 * (size_t)NND) * sizeof(float);

    dim3 blk(256);
    int gemm_grid = (NND + BM - 1) / BM;

    if (ws_size >= need_primary) {
        float* agg   = ws;
        float* asum  = ws + aggN;
        float* a_src = asum + (size_t)NND * NREL;
        float* a_tgt = a_src + NND;
        hipMemsetAsync(agg, 0, (aggN + (size_t)NND * NREL) * sizeof(float), stream);
        node_dots_kernel<<<(NND + 3) / 4, blk, 0, stream>>>(x, wa, a_src, a_tgt);
        edge_scatter_kernel<<<(NED + 7) / 8, blk, 0, stream>>>(
            ei, et, x, a_src, a_tgt, ba, agg, asum, 0, NREL, NREL);
        final_gemm_kernel<<<gemm_grid, blk, 0, stream>>>(
            x, Ws, bs, agg, asum, Wr, br, out, NREL, 1, 0);
    } else if (ws_size >= need_fallback) {
        // per-relation streaming fallback (~27 MB workspace)
        float* Y     = ws;
        float* ysum  = ws + yN;
        float* a_src = ysum + NND;
        float* a_tgt = a_src + NND;
        node_dots_kernel<<<(NND + 3) / 4, blk, 0, stream>>>(x, wa, a_src, a_tgt);
        final_gemm_kernel<<<gemm_grid, blk, 0, stream>>>(
            x, Ws, bs, nullptr, nullptr, nullptr, nullptr, out, 0, 1, 0);
        for (int r = 0; r < NREL; ++r) {
            hipMemsetAsync(Y, 0, (yN + NND) * sizeof(float), stream);
            edge_scatter_kernel<<<(NED + 7) / 8, blk, 0, stream>>>(
                ei, et, x, a_src, a_tgt, ba, Y, ysum, r, r + 1, 1);
            final_gemm_kernel<<<gemm_grid, blk, 0, stream>>>(
                nullptr, nullptr, nullptr, Y, ysum,
                Wr + (size_t)r * FDIM * FDIM, br + (size_t)r * FDIM, out, 1, 0, 1);
        }
    }
    // if ws is smaller than ~27MB there is no valid path; fail visibly.
}

// Round 2
// 446.024 us; speedup vs baseline: 2.6993x; 2.6993x over previous
//
#include <hip/hip_runtime.h>
#include <math.h>

#define NND 50000
#define NED 500000
#define FDIM 128
#define NREL 8

#define BM 64
#define BK 64
#define LDA 68   // padded LDS stride (f32): 68%32=4 -> <=2-way conflicts with x16-strided thread map

// ---------------- K1: per-node attention dots ----------------
__global__ void node_dots_kernel(const float* __restrict__ x,
                                 const float* __restrict__ wa,
                                 float* __restrict__ a_src,
                                 float* __restrict__ a_tgt) {
    int gid  = blockIdx.x * blockDim.x + threadIdx.x;
    int node = gid >> 6;          // one wave (64 lanes) per node
    int lane = threadIdx.x & 63;
    if (node >= NND) return;
    float2 v = *(const float2*)(x + (size_t)node * FDIM + lane * 2);
    float s1 = v.x * wa[2 * lane]        + v.y * wa[2 * lane + 1];
    float s2 = v.x * wa[FDIM + 2 * lane] + v.y * wa[FDIM + 2 * lane + 1];
#pragma unroll
    for (int off = 32; off > 0; off >>= 1) {
        s1 += __shfl_xor(s1, off);
        s2 += __shfl_xor(s2, off);
    }
    if (lane == 0) { a_src[node] = s1; a_tgt[node] = s2; }
}

// ---------------- sort stage: histogram by target ----------------
__global__ void hist_kernel(const int* __restrict__ ei, int* __restrict__ counts) {
    int e = blockIdx.x * blockDim.x + threadIdx.x;
    if (e >= NED) return;
    int tgt = ei[NED + e];
    atomicAdd(&counts[tgt], 1);
}

// exclusive scan of counts[NND] -> offs[NND], 1024-chunk 3-pass
__global__ void scan_pass1(const int* __restrict__ counts, int* __restrict__ offs,
                           int* __restrict__ bsum, int n) {
    __shared__ int buf[1024];
    int gid = blockIdx.x * 1024 + threadIdx.x;
    int v = (gid < n) ? counts[gid] : 0;
    buf[threadIdx.x] = v;
    __syncthreads();
    for (int d = 1; d < 1024; d <<= 1) {
        int t = (threadIdx.x >= (unsigned)d) ? buf[threadIdx.x - d] : 0;
        __syncthreads();
        buf[threadIdx.x] += t;
        __syncthreads();
    }
    if (gid < n) offs[gid] = buf[threadIdx.x] - v;       // exclusive within block
    if (threadIdx.x == 1023) bsum[blockIdx.x] = buf[1023];
}

__global__ void scan_pass2(int* __restrict__ bsum, int nb) {
    int lane = threadIdx.x;   // single wave of 64
    int v = (lane < nb) ? bsum[lane] : 0;
    int orig = v;
#pragma unroll
    for (int d = 1; d < 64; d <<= 1) {
        int t = __shfl_up(v, d);
        if (lane >= d) v += t;
    }
    if (lane < nb) bsum[lane] = v - orig;                // exclusive block offsets
}

__global__ void scan_pass3(int* __restrict__ offs, const int* __restrict__ bsum, int n) {
    int gid = blockIdx.x * 1024 + threadIdx.x;
    if (gid < n) offs[gid] += bsum[blockIdx.x];
}

// scatter packed (rel<<16)|src into CSR order. After this, offs[t] = END of segment t.
__global__ void scatter_kernel(const int* __restrict__ ei, const int* __restrict__ et,
                               int* __restrict__ offs, int* __restrict__ sorted) {
    int e = blockIdx.x * blockDim.x + threadIdx.x;
    if (e >= NED) return;
    int src = ei[e];
    int tgt = ei[NED + e];
    int rel = et[e];
    int pos = atomicAdd(&offs[tgt], 1);
    sorted[pos] = (rel << 16) | src;
}

// ---------------- K2': gather-based segmented reduction (no atomics) ----------------
// one wave per target; 8 per-relation float2 accumulators in registers.
// Writes ALL slots (zeros included) => replaces the agg/asum memset.
__global__ __launch_bounds__(256) void segsum_kernel(
        const int* __restrict__ offs, const int* __restrict__ sorted,
        const float* __restrict__ x,
        const float* __restrict__ a_src, const float* __restrict__ a_tgt,
        const float* __restrict__ ba,
        float* __restrict__ agg, float* __restrict__ asum) {
    int wid  = (blockIdx.x * blockDim.x + threadIdx.x) >> 6;  // = target node
    int lane = threadIdx.x & 63;
    if (wid >= NND) return;
    int tgt   = wid;
    int start = (tgt == 0) ? 0 : offs[tgt - 1];
    int end   = offs[tgt];
    float at = a_tgt[tgt] + ba[0];

    float2 c0 = {0,0}, c1 = {0,0}, c2 = {0,0}, c3 = {0,0};
    float2 c4 = {0,0}, c5 = {0,0}, c6 = {0,0}, c7 = {0,0};
    float s0=0,s1=0,s2=0,s3=0,s4=0,s5=0,s6=0,s7=0;

    for (int k = start; k < end; ++k) {
        int p   = sorted[k];          // wave-uniform broadcast
        int src = p & 0xFFFF;
        int rel = p >> 16;
        float a = 1.0f / (1.0f + __expf(-(a_src[src] + at)));
        float2 v = *(const float2*)(x + (size_t)src * FDIM + lane * 2);
        switch (rel) {                // rel wave-uniform -> scalar branch, no divergence
            case 0: c0.x += a*v.x; c0.y += a*v.y; s0 += a; break;
            case 1: c1.x += a*v.x; c1.y += a*v.y; s1 += a; break;
            case 2: c2.x += a*v.x; c2.y += a*v.y; s2 += a; break;
            case 3: c3.x += a*v.x; c3.y += a*v.y; s3 += a; break;
            case 4: c4.x += a*v.x; c4.y += a*v.y; s4 += a; break;
            case 5: c5.x += a*v.x; c5.y += a*v.y; s5 += a; break;
            case 6: c6.x += a*v.x; c6.y += a*v.y; s6 += a; break;
            default: c7.x += a*v.x; c7.y += a*v.y; s7 += a; break;
        }
    }
    float* base = agg + (size_t)tgt * NREL * FDIM + lane * 2;
    *(float2*)(base + 0 * FDIM) = c0;
    *(float2*)(base + 1 * FDIM) = c1;
    *(float2*)(base + 2 * FDIM) = c2;
    *(float2*)(base + 3 * FDIM) = c3;
    *(float2*)(base + 4 * FDIM) = c4;
    *(float2*)(base + 5 * FDIM) = c5;
    *(float2*)(base + 6 * FDIM) = c6;
    *(float2*)(base + 7 * FDIM) = c7;
    if (lane == 0) {
        float* ab = asum + (size_t)tgt * NREL;
        ab[0]=s0; ab[1]=s1; ab[2]=s2; ab[3]=s3; ab[4]=s4; ab[5]=s5; ab[6]=s6; ab[7]=s7;
    }
}

// ---------------- legacy K2: edge scatter (atomics) — fallback path ----------------
__global__ void edge_scatter_kernel(const int* __restrict__ ei,
                                    const int* __restrict__ et,
                                    const float* __restrict__ x,
                                    const float* __restrict__ a_src,
                                    const float* __restrict__ a_tgt,
                                    const float* __restrict__ ba,
                                    float* __restrict__ agg,
                                    float* __restrict__ asum) {
    int gid  = blockIdx.x * blockDim.x + threadIdx.x;
    int e    = gid >> 5;
    int lane = threadIdx.x & 31;
    if (e >= NED) return;
    int rel = et[e];
    int src = ei[e];
    int tgt = ei[NED + e];
    float s = a_src[src] + a_tgt[tgt] + ba[0];
    float a = 1.0f / (1.0f + __expf(-s));
    float4 v = *(const float4*)(x + (size_t)src * FDIM + lane * 4);
    size_t seg = (size_t)tgt * NREL + rel;
    float* dst = agg + seg * FDIM + lane * 4;
    atomicAdd(dst + 0, a * v.x);
    atomicAdd(dst + 1, a * v.y);
    atomicAdd(dst + 2, a * v.z);
    atomicAdd(dst + 3, a * v.w);
    if (lane == 0) atomicAdd(asum + seg, a);
}

// ---------------- K3: fused output GEMM ----------------
__global__ __launch_bounds__(256) void final_gemm_kernel(
        const float* __restrict__ x,
        const float* __restrict__ Ws,
        const float* __restrict__ bs,
        const float* __restrict__ agg,
        const float* __restrict__ asum,
        const float* __restrict__ Wr,
        const float* __restrict__ br,
        float* __restrict__ out,
        int r_eff, int include_self, int accumulate) {
    __shared__ float As[BM * LDA];     // 64 x 68
    __shared__ float Bs[FDIM * LDA];   // 128 x 68
    int tid  = threadIdx.x;
    int brow = blockIdx.x * BM;
    int tr = tid >> 4;     // 0..15
    int tc = tid & 15;     // 0..15

    float acc[4][8];
#pragma unroll
    for (int i = 0; i < 4; ++i)
#pragma unroll
        for (int j = 0; j < 8; ++j) acc[i][j] = 0.f;

    int nchunks = 2 * (include_self + r_eff);
    int arow = tid >> 2;
    int af4  = tid & 3;
    int grow = brow + arow;
    int borow = tid >> 1;
    int bf4  = tid & 1;

    for (int c = 0; c < nchunks; ++c) {
        int phase = c >> 1;
        int hlf   = c & 1;
        bool isSelf = (include_self && phase == 0);
        int rel = phase - include_self;
        const float* asrc;
        const float* bsrc;
        if (isSelf) {
            asrc = x + (size_t)grow * FDIM + hlf * BK;
            bsrc = Ws + (size_t)borow * FDIM + hlf * BK;
        } else {
            asrc = agg + ((size_t)grow * r_eff + rel) * FDIM + hlf * BK;
            bsrc = Wr + (size_t)rel * FDIM * FDIM + (size_t)borow * FDIM + hlf * BK;
        }
#pragma unroll
        for (int q = 0; q < 4; ++q) {
            int f4 = af4 + 4 * q;
            float4 v = make_float4(0.f, 0.f, 0.f, 0.f);
            if (grow < NND) v = *(const float4*)(asrc + f4 * 4);
            *(float4*)&As[arow * LDA + f4 * 4] = v;
        }
#pragma unroll
        for (int q = 0; q < 8; ++q) {
            int f4 = bf4 + 2 * q;
            *(float4*)&Bs[borow * LDA + f4 * 4] = *(const float4*)(bsrc + f4 * 4);
        }
        __syncthreads();
#pragma unroll 2
        for (int kk = 0; kk < BK; kk += 4) {
            float4 av[4];
            float4 bv[8];
#pragma unroll
            for (int i = 0; i < 4; ++i)
                av[i] = *(const float4*)&As[(i * 16 + tr) * LDA + kk];
#pragma unroll
            for (int j = 0; j < 8; ++j)
                bv[j] = *(const float4*)&Bs[(j * 16 + tc) * LDA + kk];
#pragma unroll
            for (int i = 0; i < 4; ++i)
#pragma unroll
                for (int j = 0; j < 8; ++j) {
                    acc[i][j] += av[i].x * bv[j].x;
                    acc[i][j] += av[i].y * bv[j].y;
                    acc[i][j] += av[i].z * bv[j].z;
                    acc[i][j] += av[i].w * bv[j].w;
                }
        }
        __syncthreads();
    }

    if (r_eff > 0) {
#pragma unroll
        for (int i = 0; i < 4; ++i) {
            int n = brow + i * 16 + tr;
            if (n >= NND) continue;
            for (int r = 0; r < r_eff; ++r) {
                float av = asum[(size_t)n * r_eff + r];
#pragma unroll
                for (int j = 0; j < 8; ++j)
                    acc[i][j] += av * br[(size_t)r * FDIM + j * 16 + tc];
            }
        }
    }
    if (include_self) {
#pragma unroll
        for (int j = 0; j < 8; ++j) {
            float b = bs[j * 16 + tc];
#pragma unroll
            for (int i = 0; i < 4; ++i) acc[i][j] += b;
        }
    }
#pragma unroll
    for (int i = 0; i < 4; ++i) {
        int n = brow + i * 16 + tr;
        if (n >= NND) continue;
#pragma unroll
        for (int j = 0; j < 8; ++j) {
            size_t idx = (size_t)n * FDIM + j * 16 + tc;
            if (accumulate) out[idx] += acc[i][j];
            else            out[idx] = acc[i][j];
        }
    }
}

extern "C" void kernel_launch(void* const* d_in, const int* in_sizes, int n_in,
                              void* d_out, int out_size, void* d_ws, size_t ws_size,
                              hipStream_t stream) {
    const float* x  = (const float*)d_in[0];
    const int*   ei = (const int*)d_in[1];
    const int*   et = (const int*)d_in[2];
    const float* Wr = (const float*)d_in[3];
    const float* br = (const float*)d_in[4];
    const float* Ws = (const float*)d_in[5];
    const float* bs = (const float*)d_in[6];
    const float* wa = (const float*)d_in[7];
    const float* ba = (const float*)d_in[8];
    float* out = (float*)d_out;
    float* ws  = (float*)d_ws;

    const size_t aggN  = (size_t)NND * NREL * FDIM;   // 51.2M floats
    const size_t asumN = (size_t)NND * NREL;          // 400K

    // sorted-path layout
    size_t o = 0;
    float* agg   = ws + o; o += aggN;
    float* asum  = ws + o; o += asumN;
    float* a_src = ws + o; o += NND;
    float* a_tgt = ws + o; o += NND;
    int*   counts = (int*)(ws + o); o += NND;
    int*   offs   = (int*)(ws + o); o += NND;
    int*   bsum   = (int*)(ws + o); o += 64;
    int*   sorted = (int*)(ws + o); o += NED;
    const size_t need_sorted = o * sizeof(float);
    const size_t need_atomic = (aggN + asumN + 2 * (size_t)NND) * sizeof(float);

    dim3 blk(256);
    int gemm_grid = (NND + BM - 1) / BM;
    const int nblk1024 = (NND + 1023) / 1024;   // 49

    if (ws_size >= need_sorted) {
        node_dots_kernel<<<(NND + 3) / 4, blk, 0, stream>>>(x, wa, a_src, a_tgt);
        hipMemsetAsync(counts, 0, NND * sizeof(int), stream);
        hist_kernel<<<(NED + 255) / 256, blk, 0, stream>>>(ei, counts);
        scan_pass1<<<nblk1024, 1024, 0, stream>>>(counts, offs, bsum, NND);
        scan_pass2<<<1, 64, 0, stream>>>(bsum, nblk1024);
        scan_pass3<<<nblk1024, 1024, 0, stream>>>(offs, bsum, NND);
        scatter_kernel<<<(NED + 255) / 256, blk, 0, stream>>>(ei, et, offs, sorted);
        segsum_kernel<<<(NND + 3) / 4, blk, 0, stream>>>(
            offs, sorted, x, a_src, a_tgt, ba, agg, asum);
        final_gemm_kernel<<<gemm_grid, blk, 0, stream>>>(
            x, Ws, bs, agg, asum, Wr, br, out, NREL, 1, 0);
    } else if (ws_size >= need_atomic) {
        // legacy atomic path
        float* l_asum  = ws + aggN;
        float* l_asrc  = l_asum + asumN;
        float* l_atgt  = l_asrc + NND;
        hipMemsetAsync(ws, 0, (aggN + asumN) * sizeof(float), stream);
        node_dots_kernel<<<(NND + 3) / 4, blk, 0, stream>>>(x, wa, l_asrc, l_atgt);
        edge_scatter_kernel<<<(NED + 7) / 8, blk, 0, stream>>>(
            ei, et, x, l_asrc, l_atgt, ba, ws, l_asum);
        final_gemm_kernel<<<gemm_grid, blk, 0, stream>>>(
            x, Ws, bs, ws, l_asum, Wr, br, out, NREL, 1, 0);
    }
}

// Round 3
// 196.633 us; speedup vs baseline: 6.1228x; 2.2683x over previous
//
#include <hip/hip_runtime.h>
#include <math.h>

#define NND 50000
#define NED 500000
#define FDIM 128
#define NREL 8
#define KTOT 1152            // 128 self + 8*128 relations
#define MPAD 50048           // NND rounded to 64

typedef __attribute__((ext_vector_type(8))) short short8;
typedef __attribute__((ext_vector_type(4))) float f32x4;
typedef const void __attribute__((address_space(1)))* gptr_t;
typedef void __attribute__((address_space(3)))* lptr_t;

static __device__ __forceinline__ unsigned short f2bf(float f) {
    unsigned u = __float_as_uint(f);
    u += 0x7FFFu + ((u >> 16) & 1u);   // round-to-nearest-even
    return (unsigned short)(u >> 16);
}

// ---------------- K1: per-node attention dots + bf16(x) into Abig ----------------
__global__ void node_dots_kernel(const float* __restrict__ x,
                                 const float* __restrict__ wa,
                                 float* __restrict__ a_src,
                                 float* __restrict__ a_tgt,
                                 unsigned short* __restrict__ Abig) {
    int gid  = blockIdx.x * blockDim.x + threadIdx.x;
    int node = gid >> 6;          // one wave per node
    int lane = threadIdx.x & 63;
    if (node >= NND) return;
    float2 v = *(const float2*)(x + (size_t)node * FDIM + lane * 2);
    ushort2 xb = { f2bf(v.x), f2bf(v.y) };
    *(ushort2*)(Abig + (size_t)node * KTOT + lane * 2) = xb;
    float s1 = v.x * wa[2 * lane]        + v.y * wa[2 * lane + 1];
    float s2 = v.x * wa[FDIM + 2 * lane] + v.y * wa[FDIM + 2 * lane + 1];
#pragma unroll
    for (int off = 32; off > 0; off >>= 1) {
        s1 += __shfl_xor(s1, off);
        s2 += __shfl_xor(s2, off);
    }
    if (lane == 0) { a_src[node] = s1; a_tgt[node] = s2; }
}

// ---------------- weight prep: Bt[o][k] bf16, k = [Ws row | Wr[0][o] | ... | Wr[7][o]] ----------------
__global__ void prep_bt_kernel(const float* __restrict__ Ws,
                               const float* __restrict__ Wr,
                               unsigned short* __restrict__ Bt) {
    int idx = blockIdx.x * blockDim.x + threadIdx.x;
    if (idx >= FDIM * KTOT) return;
    int o = idx / KTOT;
    int k = idx - o * KTOT;
    float v;
    if (k < FDIM) v = Ws[o * FDIM + k];
    else {
        int r = (k - FDIM) >> 7;
        int i = (k - FDIM) & 127;
        v = Wr[((size_t)r * FDIM + o) * FDIM + i];
    }
    Bt[idx] = f2bf(v);
}

// ---------------- sort stage ----------------
__global__ void hist_kernel(const int* __restrict__ ei, int* __restrict__ counts) {
    int e = blockIdx.x * blockDim.x + threadIdx.x;
    if (e >= NED) return;
    atomicAdd(&counts[ei[NED + e]], 1);
}

__global__ void scan_pass1(const int* __restrict__ counts, int* __restrict__ offs,
                           int* __restrict__ bsum, int n) {
    __shared__ int buf[1024];
    int gid = blockIdx.x * 1024 + threadIdx.x;
    int v = (gid < n) ? counts[gid] : 0;
    buf[threadIdx.x] = v;
    __syncthreads();
    for (int d = 1; d < 1024; d <<= 1) {
        int t = (threadIdx.x >= (unsigned)d) ? buf[threadIdx.x - d] : 0;
        __syncthreads();
        buf[threadIdx.x] += t;
        __syncthreads();
    }
    if (gid < n) offs[gid] = buf[threadIdx.x] - v;
    if (threadIdx.x == 1023) bsum[blockIdx.x] = buf[1023];
}

__global__ void scan_pass2(int* __restrict__ bsum, int nb) {
    int lane = threadIdx.x;
    int v = (lane < nb) ? bsum[lane] : 0;
    int orig = v;
#pragma unroll
    for (int d = 1; d < 64; d <<= 1) {
        int t = __shfl_up(v, d);
        if (lane >= d) v += t;
    }
    if (lane < nb) bsum[lane] = v - orig;
}

__global__ void scan_pass3(int* __restrict__ offs, const int* __restrict__ bsum, int n) {
    int gid = blockIdx.x * 1024 + threadIdx.x;
    if (gid < n) offs[gid] += bsum[blockIdx.x];
}

__global__ void scatter_kernel(const int* __restrict__ ei, const int* __restrict__ et,
                               int* __restrict__ offs, int* __restrict__ sorted) {
    int e = blockIdx.x * blockDim.x + threadIdx.x;
    if (e >= NED) return;
    int src = ei[e];
    int tgt = ei[NED + e];
    int rel = et[e];
    int pos = atomicAdd(&offs[tgt], 1);
    sorted[pos] = (rel << 16) | src;
}

// ---------------- K2: gather segmented reduction -> bf16 agg in Abig ----------------
__global__ __launch_bounds__(256) void segsum_kernel(
        const int* __restrict__ offs, const int* __restrict__ sorted,
        const float* __restrict__ x,
        const float* __restrict__ a_src, const float* __restrict__ a_tgt,
        const float* __restrict__ ba,
        unsigned short* __restrict__ Abig, float* __restrict__ asum) {
    int wid  = (blockIdx.x * blockDim.x + threadIdx.x) >> 6;
    int lane = threadIdx.x & 63;
    if (wid >= NND) return;
    int tgt   = wid;
    int start = (tgt == 0) ? 0 : offs[tgt - 1];
    int end   = offs[tgt];
    float at = a_tgt[tgt] + ba[0];

    float2 c0 = {0,0}, c1 = {0,0}, c2 = {0,0}, c3 = {0,0};
    float2 c4 = {0,0}, c5 = {0,0}, c6 = {0,0}, c7 = {0,0};
    float s0=0,s1=0,s2=0,s3=0,s4=0,s5=0,s6=0,s7=0;

    for (int k = start; k < end; ++k) {
        int p   = sorted[k];
        int src = p & 0xFFFF;
        int rel = p >> 16;
        float a = 1.0f / (1.0f + __expf(-(a_src[src] + at)));
        float2 v = *(const float2*)(x + (size_t)src * FDIM + lane * 2);
        switch (rel) {
            case 0: c0.x += a*v.x; c0.y += a*v.y; s0 += a; break;
            case 1: c1.x += a*v.x; c1.y += a*v.y; s1 += a; break;
            case 2: c2.x += a*v.x; c2.y += a*v.y; s2 += a; break;
            case 3: c3.x += a*v.x; c3.y += a*v.y; s3 += a; break;
            case 4: c4.x += a*v.x; c4.y += a*v.y; s4 += a; break;
            case 5: c5.x += a*v.x; c5.y += a*v.y; s5 += a; break;
            case 6: c6.x += a*v.x; c6.y += a*v.y; s6 += a; break;
            default: c7.x += a*v.x; c7.y += a*v.y; s7 += a; break;
        }
    }
    unsigned short* base = Abig + (size_t)tgt * KTOT + FDIM + lane * 2;
    ushort2 w;
    w.x = f2bf(c0.x); w.y = f2bf(c0.y); *(ushort2*)(base + 0 * FDIM) = w;
    w.x = f2bf(c1.x); w.y = f2bf(c1.y); *(ushort2*)(base + 1 * FDIM) = w;
    w.x = f2bf(c2.x); w.y = f2bf(c2.y); *(ushort2*)(base + 2 * FDIM) = w;
    w.x = f2bf(c3.x); w.y = f2bf(c3.y); *(ushort2*)(base + 3 * FDIM) = w;
    w.x = f2bf(c4.x); w.y = f2bf(c4.y); *(ushort2*)(base + 4 * FDIM) = w;
    w.x = f2bf(c5.x); w.y = f2bf(c5.y); *(ushort2*)(base + 5 * FDIM) = w;
    w.x = f2bf(c6.x); w.y = f2bf(c6.y); *(ushort2*)(base + 6 * FDIM) = w;
    w.x = f2bf(c7.x); w.y = f2bf(c7.y); *(ushort2*)(base + 7 * FDIM) = w;
    if (lane == 0) {
        float* ab = asum + (size_t)tgt * NREL;
        ab[0]=s0; ab[1]=s1; ab[2]=s2; ab[3]=s3; ab[4]=s4; ab[5]=s5; ab[6]=s6; ab[7]=s7;
    }
}

// ---------------- K3: bf16 MFMA GEMM: out = Abig(50048x1152) @ Bt^T + epilogue ----------------
// BM=64, BN=128, BK=64; 4 waves, each 32x64 (2x4 frags of 16x16x32).
// LDS linear dest (global_load_lds), inverse-swizzled global source, XOR-swizzled ds_read (T2/rule21).
__global__ __launch_bounds__(256) void mfma_gemm_kernel(
        const unsigned short* __restrict__ Abig,
        const unsigned short* __restrict__ Bt,
        const float* __restrict__ asum,
        const float* __restrict__ br,
        const float* __restrict__ bs,
        float* __restrict__ out) {
    __shared__ __align__(16) unsigned short AsB[64 * 64];    // 8 KB
    __shared__ __align__(16) unsigned short BsB[128 * 64];   // 16 KB
    int tid  = threadIdx.x;
    int wave = tid >> 6;
    int lane = tid & 63;
    int l15  = lane & 15;
    int lhi  = lane >> 4;
    int brow = blockIdx.x * 64;
    int wr = wave >> 1;          // 0..1 (row half)
    int wc = wave & 1;           // 0..1 (col half)

    f32x4 acc[2][4];
#pragma unroll
    for (int mi = 0; mi < 2; ++mi)
#pragma unroll
        for (int ni = 0; ni < 4; ++ni) acc[mi][ni] = (f32x4){0.f, 0.f, 0.f, 0.f};

    for (int kc = 0; kc < KTOT / 64; ++kc) {
        // stage A: 64x64 bf16 = 8KB; linear LDS dest, source col8 pre-XOR'd with row
#pragma unroll
        for (int q = 0; q < 2; ++q) {
            int c    = tid + q * 256;          // 0..511 16B-chunks
            int trow = c >> 3;
            int csw  = (c & 7) ^ (trow & 7);
            const unsigned short* src = Abig + (size_t)(brow + trow) * KTOT + kc * 64 + csw * 8;
            __builtin_amdgcn_global_load_lds((gptr_t)src,
                (lptr_t)&AsB[wave * 512 + q * 2048], 16, 0, 0);
        }
        // stage B: 128x64 bf16 = 16KB
#pragma unroll
        for (int q = 0; q < 4; ++q) {
            int c   = tid + q * 256;           // 0..1023
            int o   = c >> 3;
            int csw = (c & 7) ^ (o & 7);
            const unsigned short* src = Bt + (size_t)o * KTOT + kc * 64 + csw * 8;
            __builtin_amdgcn_global_load_lds((gptr_t)src,
                (lptr_t)&BsB[wave * 512 + q * 2048], 16, 0, 0);
        }
        __syncthreads();
#pragma unroll
        for (int ks = 0; ks < 2; ++ks) {
            int kslot = ks * 4 + lhi;          // k0>>3
            short8 a[2], b[4];
#pragma unroll
            for (int mi = 0; mi < 2; ++mi) {
                int row = wr * 32 + mi * 16 + l15;
                a[mi] = *(const short8*)&AsB[row * 64 + ((kslot ^ (row & 7)) << 3)];
            }
#pragma unroll
            for (int ni = 0; ni < 4; ++ni) {
                int o = wc * 64 + ni * 16 + l15;
                b[ni] = *(const short8*)&BsB[o * 64 + ((kslot ^ (o & 7)) << 3)];
            }
#pragma unroll
            for (int mi = 0; mi < 2; ++mi)
#pragma unroll
                for (int ni = 0; ni < 4; ++ni)
                    acc[mi][ni] = __builtin_amdgcn_mfma_f32_16x16x32_bf16(
                        a[mi], b[ni], acc[mi][ni], 0, 0, 0);
        }
        __syncthreads();
    }

    // epilogue: + bs[col] + sum_r asum[row][r]*br[r][col]
#pragma unroll
    for (int mi = 0; mi < 2; ++mi) {
        int rowbase = brow + wr * 32 + mi * 16 + lhi * 4;
#pragma unroll
        for (int j = 0; j < 4; ++j) {
            int row = rowbase + j;
            if (row >= NND) continue;
            const float* as = asum + (size_t)row * NREL;
            float4 sa = *(const float4*)as;
            float4 sb = *(const float4*)(as + 4);
#pragma unroll
            for (int ni = 0; ni < 4; ++ni) {
                int col = wc * 64 + ni * 16 + l15;
                float v = acc[mi][ni][j] + bs[col];
                v += sa.x * br[0 * FDIM + col] + sa.y * br[1 * FDIM + col]
                   + sa.z * br[2 * FDIM + col] + sa.w * br[3 * FDIM + col];
                v += sb.x * br[4 * FDIM + col] + sb.y * br[5 * FDIM + col]
                   + sb.z * br[6 * FDIM + col] + sb.w * br[7 * FDIM + col];
                out[(size_t)row * FDIM + col] = v;
            }
        }
    }
}

extern "C" void kernel_launch(void* const* d_in, const int* in_sizes, int n_in,
                              void* d_out, int out_size, void* d_ws, size_t ws_size,
                              hipStream_t stream) {
    const float* x  = (const float*)d_in[0];
    const int*   ei = (const int*)d_in[1];
    const int*   et = (const int*)d_in[2];
    const float* Wr = (const float*)d_in[3];
    const float* br = (const float*)d_in[4];
    const float* Ws = (const float*)d_in[5];
    const float* bs = (const float*)d_in[6];
    const float* wa = (const float*)d_in[7];
    const float* ba = (const float*)d_in[8];
    float* out = (float*)d_out;
    float* ws  = (float*)d_ws;

    // workspace layout (float units)
    const size_t abigF = ((size_t)MPAD * KTOT) / 2;           // bf16 A matrix, 115.3 MB
    const size_t btF   = ((size_t)FDIM * KTOT) / 2;           // bf16 weights
    size_t o = 0;
    unsigned short* Abig = (unsigned short*)(ws + o); o += abigF;
    unsigned short* Bt   = (unsigned short*)(ws + o); o += btF;
    float* asum  = ws + o; o += (size_t)NND * NREL;
    float* a_src = ws + o; o += NND;
    float* a_tgt = ws + o; o += NND;
    int*   counts = (int*)(ws + o); o += NND;
    int*   offs   = (int*)(ws + o); o += NND;
    int*   bsum   = (int*)(ws + o); o += 64;
    int*   sorted = (int*)(ws + o); o += NED;
    if (ws_size < o * sizeof(float)) return;   // (round 1/2 verified ws >= 207 MB)

    dim3 blk(256);
    const int nblk1024 = (NND + 1023) / 1024;

    // zero pad rows of Abig (rows 50000..50047) once per call — keeps MFMA inputs finite
    hipMemsetAsync(Abig + (size_t)NND * KTOT, 0, (size_t)(MPAD - NND) * KTOT * 2, stream);
    hipMemsetAsync(counts, 0, NND * sizeof(int), stream);

    node_dots_kernel<<<(NND + 3) / 4, blk, 0, stream>>>(x, wa, a_src, a_tgt, Abig);
    prep_bt_kernel<<<(FDIM * KTOT + 255) / 256, blk, 0, stream>>>(Ws, Wr, Bt);
    hist_kernel<<<(NED + 255) / 256, blk, 0, stream>>>(ei, counts);
    scan_pass1<<<nblk1024, 1024, 0, stream>>>(counts, offs, bsum, NND);
    scan_pass2<<<1, 64, 0, stream>>>(bsum, nblk1024);
    scan_pass3<<<nblk1024, 1024, 0, stream>>>(offs, bsum, NND);
    scatter_kernel<<<(NED + 255) / 256, blk, 0, stream>>>(ei, et, offs, sorted);
    segsum_kernel<<<(NND + 3) / 4, blk, 0, stream>>>(
        offs, sorted, x, a_src, a_tgt, ba, Abig, asum);
    mfma_gemm_kernel<<<MPAD / 64, blk, 0, stream>>>(Abig, Bt, asum, br, bs, out);
}

// Round 4
// 184.047 us; speedup vs baseline: 6.5415x; 1.0684x over previous
//
#include <hip/hip_runtime.h>
#include <math.h>

#define NND 50000
#define NED 500000
#define FDIM 128
#define NREL 8
#define KTOT 1152            // 128 self + 8*128 relations
#define MPAD 50048           // NND rounded to 64

typedef __attribute__((ext_vector_type(8))) short short8;
typedef __attribute__((ext_vector_type(4))) float f32x4;
typedef const void __attribute__((address_space(1)))* gptr_t;
typedef void __attribute__((address_space(3)))* lptr_t;

static __device__ __forceinline__ unsigned short f2bf(float f) {
    unsigned u = __float_as_uint(f);
    u += 0x7FFFu + ((u >> 16) & 1u);   // round-to-nearest-even
    return (unsigned short)(u >> 16);
}
static __device__ __forceinline__ float bf2f(unsigned short b) {
    return __uint_as_float((unsigned)b << 16);
}

// ---------------- K1: per-node attention dots + bf16(x) into Abig and xb ----------------
__global__ void node_dots_kernel(const float* __restrict__ x,
                                 const float* __restrict__ wa,
                                 float* __restrict__ a_src,
                                 float* __restrict__ a_tgt,
                                 unsigned short* __restrict__ Abig,
                                 unsigned short* __restrict__ xb) {
    int gid  = blockIdx.x * blockDim.x + threadIdx.x;
    int node = gid >> 6;          // one wave per node
    int lane = threadIdx.x & 63;
    if (node >= NND) return;
    float2 v = *(const float2*)(x + (size_t)node * FDIM + lane * 2);
    ushort2 vb = { f2bf(v.x), f2bf(v.y) };
    *(ushort2*)(Abig + (size_t)node * KTOT + lane * 2) = vb;
    *(ushort2*)(xb   + (size_t)node * FDIM + lane * 2) = vb;
    float s1 = v.x * wa[2 * lane]        + v.y * wa[2 * lane + 1];
    float s2 = v.x * wa[FDIM + 2 * lane] + v.y * wa[FDIM + 2 * lane + 1];
#pragma unroll
    for (int off = 32; off > 0; off >>= 1) {
        s1 += __shfl_xor(s1, off);
        s2 += __shfl_xor(s2, off);
    }
    if (lane == 0) { a_src[node] = s1; a_tgt[node] = s2; }
}

// ---------------- weight prep: Bt[o][k] bf16 ----------------
__global__ void prep_bt_kernel(const float* __restrict__ Ws,
                               const float* __restrict__ Wr,
                               unsigned short* __restrict__ Bt) {
    int idx = blockIdx.x * blockDim.x + threadIdx.x;
    if (idx >= FDIM * KTOT) return;
    int o = idx / KTOT;
    int k = idx - o * KTOT;
    float v;
    if (k < FDIM) v = Ws[o * FDIM + k];
    else {
        int r = (k - FDIM) >> 7;
        int i = (k - FDIM) & 127;
        v = Wr[((size_t)r * FDIM + o) * FDIM + i];
    }
    Bt[idx] = f2bf(v);
}

// ---------------- sort stage ----------------
__global__ void hist_kernel(const int* __restrict__ ei, int* __restrict__ counts) {
    int e = blockIdx.x * blockDim.x + threadIdx.x;
    if (e >= NED) return;
    atomicAdd(&counts[ei[NED + e]], 1);
}

__global__ void scan_pass1(const int* __restrict__ counts, int* __restrict__ offs,
                           int* __restrict__ bsum, int n) {
    __shared__ int buf[1024];
    int gid = blockIdx.x * 1024 + threadIdx.x;
    int v = (gid < n) ? counts[gid] : 0;
    buf[threadIdx.x] = v;
    __syncthreads();
    for (int d = 1; d < 1024; d <<= 1) {
        int t = (threadIdx.x >= (unsigned)d) ? buf[threadIdx.x - d] : 0;
        __syncthreads();
        buf[threadIdx.x] += t;
        __syncthreads();
    }
    if (gid < n) offs[gid] = buf[threadIdx.x] - v;
    if (threadIdx.x == 1023) bsum[blockIdx.x] = buf[1023];
}

__global__ void scan_pass2(int* __restrict__ bsum, int nb) {
    int lane = threadIdx.x;
    int v = (lane < nb) ? bsum[lane] : 0;
    int orig = v;
#pragma unroll
    for (int d = 1; d < 64; d <<= 1) {
        int t = __shfl_up(v, d);
        if (lane >= d) v += t;
    }
    if (lane < nb) bsum[lane] = v - orig;
}

__global__ void scan_pass3(int* __restrict__ offs, const int* __restrict__ bsum, int n) {
    int gid = blockIdx.x * 1024 + threadIdx.x;
    if (gid < n) offs[gid] += bsum[blockIdx.x];
}

// scatter: compute sigmoid ONCE per edge, store {a, (rel<<16)|src} as 8-byte entry
__global__ void scatter_kernel(const int* __restrict__ ei, const int* __restrict__ et,
                               const float* __restrict__ a_src, const float* __restrict__ a_tgt,
                               const float* __restrict__ ba,
                               int* __restrict__ offs,
                               unsigned long long* __restrict__ sorted2) {
    int e = blockIdx.x * blockDim.x + threadIdx.x;
    if (e >= NED) return;
    int src = ei[e];
    int tgt = ei[NED + e];
    int rel = et[e];
    float s = a_src[src] + a_tgt[tgt] + ba[0];
    float a = 1.0f / (1.0f + __expf(-s));
    int pos = atomicAdd(&offs[tgt], 1);
    unsigned long long pk = ((unsigned long long)__float_as_uint(a) << 32)
                          | (unsigned)((rel << 16) | src);
    sorted2[pos] = pk;
}

// ---------------- K2: gather segmented reduction (bf16 gathers, no exp) ----------------
__global__ __launch_bounds__(256) void segsum_kernel(
        const int* __restrict__ offs, const unsigned long long* __restrict__ sorted2,
        const unsigned short* __restrict__ xb,
        unsigned short* __restrict__ Abig, float* __restrict__ asum) {
    int wid  = (blockIdx.x * blockDim.x + threadIdx.x) >> 6;
    int lane = threadIdx.x & 63;
    if (wid >= NND) return;
    int tgt   = wid;
    int start = (tgt == 0) ? 0 : offs[tgt - 1];
    int end   = offs[tgt];

    float2 c0 = {0,0}, c1 = {0,0}, c2 = {0,0}, c3 = {0,0};
    float2 c4 = {0,0}, c5 = {0,0}, c6 = {0,0}, c7 = {0,0};
    float s0=0,s1=0,s2=0,s3=0,s4=0,s5=0,s6=0,s7=0;

    for (int k = start; k < end; ++k) {
        unsigned long long pk = sorted2[k];          // wave-uniform broadcast
        float a  = __uint_as_float((unsigned)(pk >> 32));
        int  src = (int)(pk & 0xFFFF);
        int  rel = (int)((pk >> 16) & 0xF);
        ushort2 w = *(const ushort2*)(xb + (size_t)src * FDIM + lane * 2);
        float vx = bf2f(w.x), vy = bf2f(w.y);
        switch (rel) {                               // rel wave-uniform -> scalar branch
            case 0: c0.x += a*vx; c0.y += a*vy; s0 += a; break;
            case 1: c1.x += a*vx; c1.y += a*vy; s1 += a; break;
            case 2: c2.x += a*vx; c2.y += a*vy; s2 += a; break;
            case 3: c3.x += a*vx; c3.y += a*vy; s3 += a; break;
            case 4: c4.x += a*vx; c4.y += a*vy; s4 += a; break;
            case 5: c5.x += a*vx; c5.y += a*vy; s5 += a; break;
            case 6: c6.x += a*vx; c6.y += a*vy; s6 += a; break;
            default: c7.x += a*vx; c7.y += a*vy; s7 += a; break;
        }
    }
    unsigned short* base = Abig + (size_t)tgt * KTOT + FDIM + lane * 2;
    ushort2 w;
    w.x = f2bf(c0.x); w.y = f2bf(c0.y); *(ushort2*)(base + 0 * FDIM) = w;
    w.x = f2bf(c1.x); w.y = f2bf(c1.y); *(ushort2*)(base + 1 * FDIM) = w;
    w.x = f2bf(c2.x); w.y = f2bf(c2.y); *(ushort2*)(base + 2 * FDIM) = w;
    w.x = f2bf(c3.x); w.y = f2bf(c3.y); *(ushort2*)(base + 3 * FDIM) = w;
    w.x = f2bf(c4.x); w.y = f2bf(c4.y); *(ushort2*)(base + 4 * FDIM) = w;
    w.x = f2bf(c5.x); w.y = f2bf(c5.y); *(ushort2*)(base + 5 * FDIM) = w;
    w.x = f2bf(c6.x); w.y = f2bf(c6.y); *(ushort2*)(base + 6 * FDIM) = w;
    w.x = f2bf(c7.x); w.y = f2bf(c7.y); *(ushort2*)(base + 7 * FDIM) = w;
    if (lane == 0) {
        float* ab = asum + (size_t)tgt * NREL;
        ab[0]=s0; ab[1]=s1; ab[2]=s2; ab[3]=s3; ab[4]=s4; ab[5]=s5; ab[6]=s6; ab[7]=s7;
    }
}

// ---------------- K3: bf16 MFMA GEMM: out = Abig(50048x1152) @ Bt^T + epilogue ----------------
__global__ __launch_bounds__(256) void mfma_gemm_kernel(
        const unsigned short* __restrict__ Abig,
        const unsigned short* __restrict__ Bt,
        const float* __restrict__ asum,
        const float* __restrict__ br,
        const float* __restrict__ bs,
        float* __restrict__ out) {
    __shared__ __align__(16) unsigned short AsB[64 * 64];    // 8 KB
    __shared__ __align__(16) unsigned short BsB[128 * 64];   // 16 KB
    int tid  = threadIdx.x;
    int wave = tid >> 6;
    int lane = tid & 63;
    int l15  = lane & 15;
    int lhi  = lane >> 4;
    int brow = blockIdx.x * 64;
    int wr = wave >> 1;          // 0..1
    int wc = wave & 1;           // 0..1

    f32x4 acc[2][4];
#pragma unroll
    for (int mi = 0; mi < 2; ++mi)
#pragma unroll
        for (int ni = 0; ni < 4; ++ni) acc[mi][ni] = (f32x4){0.f, 0.f, 0.f, 0.f};

    for (int kc = 0; kc < KTOT / 64; ++kc) {
#pragma unroll
        for (int q = 0; q < 2; ++q) {
            int c    = tid + q * 256;
            int trow = c >> 3;
            int csw  = (c & 7) ^ (trow & 7);
            const unsigned short* src = Abig + (size_t)(brow + trow) * KTOT + kc * 64 + csw * 8;
            __builtin_amdgcn_global_load_lds((gptr_t)src,
                (lptr_t)&AsB[wave * 512 + q * 2048], 16, 0, 0);
        }
#pragma unroll
        for (int q = 0; q < 4; ++q) {
            int c   = tid + q * 256;
            int o   = c >> 3;
            int csw = (c & 7) ^ (o & 7);
            const unsigned short* src = Bt + (size_t)o * KTOT + kc * 64 + csw * 8;
            __builtin_amdgcn_global_load_lds((gptr_t)src,
                (lptr_t)&BsB[wave * 512 + q * 2048], 16, 0, 0);
        }
        __syncthreads();
#pragma unroll
        for (int ks = 0; ks < 2; ++ks) {
            int kslot = ks * 4 + lhi;
            short8 a[2], b[4];
#pragma unroll
            for (int mi = 0; mi < 2; ++mi) {
                int row = wr * 32 + mi * 16 + l15;
                a[mi] = *(const short8*)&AsB[row * 64 + ((kslot ^ (row & 7)) << 3)];
            }
#pragma unroll
            for (int ni = 0; ni < 4; ++ni) {
                int o = wc * 64 + ni * 16 + l15;
                b[ni] = *(const short8*)&BsB[o * 64 + ((kslot ^ (o & 7)) << 3)];
            }
#pragma unroll
            for (int mi = 0; mi < 2; ++mi)
#pragma unroll
                for (int ni = 0; ni < 4; ++ni)
                    acc[mi][ni] = __builtin_amdgcn_mfma_f32_16x16x32_bf16(
                        a[mi], b[ni], acc[mi][ni], 0, 0, 0);
        }
        __syncthreads();
    }

#pragma unroll
    for (int mi = 0; mi < 2; ++mi) {
        int rowbase = brow + wr * 32 + mi * 16 + lhi * 4;
#pragma unroll
        for (int j = 0; j < 4; ++j) {
            int row = rowbase + j;
            if (row >= NND) continue;
            const float* as = asum + (size_t)row * NREL;
            float4 sa = *(const float4*)as;
            float4 sb = *(const float4*)(as + 4);
#pragma unroll
            for (int ni = 0; ni < 4; ++ni) {
                int col = wc * 64 + ni * 16 + l15;
                float v = acc[mi][ni][j] + bs[col];
                v += sa.x * br[0 * FDIM + col] + sa.y * br[1 * FDIM + col]
                   + sa.z * br[2 * FDIM + col] + sa.w * br[3 * FDIM + col];
                v += sb.x * br[4 * FDIM + col] + sb.y * br[5 * FDIM + col]
                   + sb.z * br[6 * FDIM + col] + sb.w * br[7 * FDIM + col];
                out[(size_t)row * FDIM + col] = v;
            }
        }
    }
}

extern "C" void kernel_launch(void* const* d_in, const int* in_sizes, int n_in,
                              void* d_out, int out_size, void* d_ws, size_t ws_size,
                              hipStream_t stream) {
    const float* x  = (const float*)d_in[0];
    const int*   ei = (const int*)d_in[1];
    const int*   et = (const int*)d_in[2];
    const float* Wr = (const float*)d_in[3];
    const float* br = (const float*)d_in[4];
    const float* Ws = (const float*)d_in[5];
    const float* bs = (const float*)d_in[6];
    const float* wa = (const float*)d_in[7];
    const float* ba = (const float*)d_in[8];
    float* out = (float*)d_out;
    float* ws  = (float*)d_ws;

    // workspace layout (float units; all offsets even -> 8B alignment for sorted2)
    const size_t abigF = ((size_t)MPAD * KTOT) / 2;
    const size_t btF   = ((size_t)FDIM * KTOT) / 2;
    const size_t xbF   = ((size_t)NND * FDIM) / 2;
    size_t o = 0;
    unsigned short* Abig = (unsigned short*)(ws + o); o += abigF;
    unsigned short* Bt   = (unsigned short*)(ws + o); o += btF;
    unsigned short* xb   = (unsigned short*)(ws + o); o += xbF;
    float* asum  = ws + o; o += (size_t)NND * NREL;
    float* a_src = ws + o; o += NND;
    float* a_tgt = ws + o; o += NND;
    int*   counts = (int*)(ws + o); o += NND;
    int*   offs   = (int*)(ws + o); o += NND;
    int*   bsum   = (int*)(ws + o); o += 64;
    unsigned long long* sorted2 = (unsigned long long*)(ws + o); o += 2 * (size_t)NED;
    if (ws_size < o * sizeof(float)) return;

    dim3 blk(256);
    const int nblk1024 = (NND + 1023) / 1024;

    hipMemsetAsync(Abig + (size_t)NND * KTOT, 0, (size_t)(MPAD - NND) * KTOT * 2, stream);
    hipMemsetAsync(counts, 0, NND * sizeof(int), stream);

    node_dots_kernel<<<(NND + 3) / 4, blk, 0, stream>>>(x, wa, a_src, a_tgt, Abig, xb);
    prep_bt_kernel<<<(FDIM * KTOT + 255) / 256, blk, 0, stream>>>(Ws, Wr, Bt);
    hist_kernel<<<(NED + 255) / 256, blk, 0, stream>>>(ei, counts);
    scan_pass1<<<nblk1024, 1024, 0, stream>>>(counts, offs, bsum, NND);
    scan_pass2<<<1, 64, 0, stream>>>(bsum, nblk1024);
    scan_pass3<<<nblk1024, 1024, 0, stream>>>(offs, bsum, NND);
    scatter_kernel<<<(NED + 255) / 256, blk, 0, stream>>>(ei, et, a_src, a_tgt, ba, offs, sorted2);
    segsum_kernel<<<(NND + 3) / 4, blk, 0, stream>>>(offs, sorted2, xb, Abig, asum);
    mfma_gemm_kernel<<<MPAD / 64, blk, 0, stream>>>(Abig, Bt, asum, br, bs, out);
}

// Round 5
// 158.347 us; speedup vs baseline: 7.6032x; 1.1623x over previous
//
#include <hip/hip_runtime.h>
#include <math.h>

#define NND 50000
#define NED 500000
#define FDIM 128
#define NREL 8
#define KTOT 1152            // 128 self + 8*128 relations
#define MPAD 50048           // NND rounded to 64

typedef __attribute__((ext_vector_type(8))) short short8;
typedef __attribute__((ext_vector_type(4))) float f32x4;
typedef const void __attribute__((address_space(1)))* gptr_t;
typedef void __attribute__((address_space(3)))* lptr_t;

static __device__ __forceinline__ unsigned short f2bf(float f) {
    unsigned u = __float_as_uint(f);
    u += 0x7FFFu + ((u >> 16) & 1u);   // round-to-nearest-even
    return (unsigned short)(u >> 16);
}
static __device__ __forceinline__ float bf2f(unsigned short b) {
    return __uint_as_float((unsigned)b << 16);
}

// ---------------- K1: per-node attention dots + bf16(x) into Abig and xb ----------------
__global__ void node_dots_kernel(const float* __restrict__ x,
                                 const float* __restrict__ wa,
                                 float* __restrict__ a_src,
                                 float* __restrict__ a_tgt,
                                 unsigned short* __restrict__ Abig,
                                 unsigned short* __restrict__ xb) {
    int gid  = blockIdx.x * blockDim.x + threadIdx.x;
    int node = gid >> 6;          // one wave per node
    int lane = threadIdx.x & 63;
    if (node >= NND) return;
    float2 v = *(const float2*)(x + (size_t)node * FDIM + lane * 2);
    ushort2 vb = { f2bf(v.x), f2bf(v.y) };
    *(ushort2*)(Abig + (size_t)node * KTOT + lane * 2) = vb;
    *(ushort2*)(xb   + (size_t)node * FDIM + lane * 2) = vb;
    float s1 = v.x * wa[2 * lane]        + v.y * wa[2 * lane + 1];
    float s2 = v.x * wa[FDIM + 2 * lane] + v.y * wa[FDIM + 2 * lane + 1];
#pragma unroll
    for (int off = 32; off > 0; off >>= 1) {
        s1 += __shfl_xor(s1, off);
        s2 += __shfl_xor(s2, off);
    }
    if (lane == 0) { a_src[node] = s1; a_tgt[node] = s2; }
}

// ---------------- weight prep: Bt[o][k] bf16 ----------------
__global__ void prep_bt_kernel(const float* __restrict__ Ws,
                               const float* __restrict__ Wr,
                               unsigned short* __restrict__ Bt) {
    int idx = blockIdx.x * blockDim.x + threadIdx.x;
    if (idx >= FDIM * KTOT) return;
    int o = idx / KTOT;
    int k = idx - o * KTOT;
    float v;
    if (k < FDIM) v = Ws[o * FDIM + k];
    else {
        int r = (k - FDIM) >> 7;
        int i = (k - FDIM) & 127;
        v = Wr[((size_t)r * FDIM + o) * FDIM + i];
    }
    Bt[idx] = f2bf(v);
}

// ---------------- sort stage ----------------
__global__ void hist_kernel(const int* __restrict__ ei, int* __restrict__ counts) {
    int e = blockIdx.x * blockDim.x + threadIdx.x;
    if (e >= NED) return;
    atomicAdd(&counts[ei[NED + e]], 1);
}

__global__ void scan_pass1(const int* __restrict__ counts, int* __restrict__ offs,
                           int* __restrict__ bsum, int n) {
    __shared__ int buf[1024];
    int gid = blockIdx.x * 1024 + threadIdx.x;
    int v = (gid < n) ? counts[gid] : 0;
    buf[threadIdx.x] = v;
    __syncthreads();
    for (int d = 1; d < 1024; d <<= 1) {
        int t = (threadIdx.x >= (unsigned)d) ? buf[threadIdx.x - d] : 0;
        __syncthreads();
        buf[threadIdx.x] += t;
        __syncthreads();
    }
    if (gid < n) offs[gid] = buf[threadIdx.x] - v;
    if (threadIdx.x == 1023) bsum[blockIdx.x] = buf[1023];
}

__global__ void scan_pass2(int* __restrict__ bsum, int nb) {
    int lane = threadIdx.x;
    int v = (lane < nb) ? bsum[lane] : 0;
    int orig = v;
#pragma unroll
    for (int d = 1; d < 64; d <<= 1) {
        int t = __shfl_up(v, d);
        if (lane >= d) v += t;
    }
    if (lane < nb) bsum[lane] = v - orig;
}

__global__ void scan_pass3(int* __restrict__ offs, const int* __restrict__ bsum, int n) {
    int gid = blockIdx.x * 1024 + threadIdx.x;
    if (gid < n) offs[gid] += bsum[blockIdx.x];
}

// scatter: compute sigmoid ONCE per edge, store {a, (rel<<16)|src} as 8-byte entry
__global__ void scatter_kernel(const int* __restrict__ ei, const int* __restrict__ et,
                               const float* __restrict__ a_src, const float* __restrict__ a_tgt,
                               const float* __restrict__ ba,
                               int* __restrict__ offs,
                               unsigned long long* __restrict__ sorted2) {
    int e = blockIdx.x * blockDim.x + threadIdx.x;
    if (e >= NED) return;
    int src = ei[e];
    int tgt = ei[NED + e];
    int rel = et[e];
    float s = a_src[src] + a_tgt[tgt] + ba[0];
    float a = 1.0f / (1.0f + __expf(-s));
    int pos = atomicAdd(&offs[tgt], 1);
    unsigned long long pk = ((unsigned long long)__float_as_uint(a) << 32)
                          | (unsigned)((rel << 16) | src);
    sorted2[pos] = pk;
}

// ---------------- K2: gather segmented reduction, 4-deep edge batching ----------------
__global__ __launch_bounds__(256) void segsum_kernel(
        const int* __restrict__ offs, const unsigned long long* __restrict__ sorted2,
        const unsigned short* __restrict__ xb,
        unsigned short* __restrict__ Abig, float* __restrict__ asum) {
    int wid  = (blockIdx.x * blockDim.x + threadIdx.x) >> 6;
    int lane = threadIdx.x & 63;
    if (wid >= NND) return;
    int tgt   = wid;
    int start = (tgt == 0) ? 0 : offs[tgt - 1];
    int end   = offs[tgt];

    float2 c0 = {0,0}, c1 = {0,0}, c2 = {0,0}, c3 = {0,0};
    float2 c4 = {0,0}, c5 = {0,0}, c6 = {0,0}, c7 = {0,0};
    float s0=0,s1=0,s2=0,s3=0,s4=0,s5=0,s6=0,s7=0;

    const ushort2* xl = (const ushort2*)xb + lane;   // lane's 4B slot; row stride 64

#define ACC(PK, W) {                                                    \
        float a  = __uint_as_float((unsigned)((PK) >> 32));             \
        int  rel = (int)(((PK) >> 16) & 0xF);                           \
        float vx = bf2f((W).x), vy = bf2f((W).y);                       \
        switch (rel) {                                                  \
            case 0: c0.x += a*vx; c0.y += a*vy; s0 += a; break;         \
            case 1: c1.x += a*vx; c1.y += a*vy; s1 += a; break;         \
            case 2: c2.x += a*vx; c2.y += a*vy; s2 += a; break;         \
            case 3: c3.x += a*vx; c3.y += a*vy; s3 += a; break;         \
            case 4: c4.x += a*vx; c4.y += a*vy; s4 += a; break;         \
            case 5: c5.x += a*vx; c5.y += a*vy; s5 += a; break;         \
            case 6: c6.x += a*vx; c6.y += a*vy; s6 += a; break;         \
            default: c7.x += a*vx; c7.y += a*vy; s7 += a; break;        \
        }                                                               \
    }

    int k = start;
    for (; k + 4 <= end; k += 4) {
        // 4 independent metadata loads, then 4 independent gathers -> MLP x4
        unsigned long long pk0 = sorted2[k];
        unsigned long long pk1 = sorted2[k + 1];
        unsigned long long pk2 = sorted2[k + 2];
        unsigned long long pk3 = sorted2[k + 3];
        ushort2 w0 = xl[(size_t)(pk0 & 0xFFFF) * 64];
        ushort2 w1 = xl[(size_t)(pk1 & 0xFFFF) * 64];
        ushort2 w2 = xl[(size_t)(pk2 & 0xFFFF) * 64];
        ushort2 w3 = xl[(size_t)(pk3 & 0xFFFF) * 64];
        ACC(pk0, w0);
        ACC(pk1, w1);
        ACC(pk2, w2);
        ACC(pk3, w3);
    }
    for (; k < end; ++k) {
        unsigned long long pk = sorted2[k];
        ushort2 w = xl[(size_t)(pk & 0xFFFF) * 64];
        ACC(pk, w);
    }
#undef ACC

    unsigned short* base = Abig + (size_t)tgt * KTOT + FDIM + lane * 2;
    ushort2 w;
    w.x = f2bf(c0.x); w.y = f2bf(c0.y); *(ushort2*)(base + 0 * FDIM) = w;
    w.x = f2bf(c1.x); w.y = f2bf(c1.y); *(ushort2*)(base + 1 * FDIM) = w;
    w.x = f2bf(c2.x); w.y = f2bf(c2.y); *(ushort2*)(base + 2 * FDIM) = w;
    w.x = f2bf(c3.x); w.y = f2bf(c3.y); *(ushort2*)(base + 3 * FDIM) = w;
    w.x = f2bf(c4.x); w.y = f2bf(c4.y); *(ushort2*)(base + 4 * FDIM) = w;
    w.x = f2bf(c5.x); w.y = f2bf(c5.y); *(ushort2*)(base + 5 * FDIM) = w;
    w.x = f2bf(c6.x); w.y = f2bf(c6.y); *(ushort2*)(base + 6 * FDIM) = w;
    w.x = f2bf(c7.x); w.y = f2bf(c7.y); *(ushort2*)(base + 7 * FDIM) = w;
    if (lane == 0) {
        float* ab = asum + (size_t)tgt * NREL;
        ab[0]=s0; ab[1]=s1; ab[2]=s2; ab[3]=s3; ab[4]=s4; ab[5]=s5; ab[6]=s6; ab[7]=s7;
    }
}

// ---------------- K3: bf16 MFMA GEMM: out = Abig(50048x1152) @ Bt^T + epilogue ----------------
__global__ __launch_bounds__(256) void mfma_gemm_kernel(
        const unsigned short* __restrict__ Abig,
        const unsigned short* __restrict__ Bt,
        const float* __restrict__ asum,
        const float* __restrict__ br,
        const float* __restrict__ bs,
        float* __restrict__ out) {
    __shared__ __align__(16) unsigned short AsB[64 * 64];    // 8 KB
    __shared__ __align__(16) unsigned short BsB[128 * 64];   // 16 KB
    int tid  = threadIdx.x;
    int wave = tid >> 6;
    int lane = tid & 63;
    int l15  = lane & 15;
    int lhi  = lane >> 4;
    int brow = blockIdx.x * 64;
    int wr = wave >> 1;          // 0..1
    int wc = wave & 1;           // 0..1

    f32x4 acc[2][4];
#pragma unroll
    for (int mi = 0; mi < 2; ++mi)
#pragma unroll
        for (int ni = 0; ni < 4; ++ni) acc[mi][ni] = (f32x4){0.f, 0.f, 0.f, 0.f};

    for (int kc = 0; kc < KTOT / 64; ++kc) {
#pragma unroll
        for (int q = 0; q < 2; ++q) {
            int c    = tid + q * 256;
            int trow = c >> 3;
            int csw  = (c & 7) ^ (trow & 7);
            const unsigned short* src = Abig + (size_t)(brow + trow) * KTOT + kc * 64 + csw * 8;
            __builtin_amdgcn_global_load_lds((gptr_t)src,
                (lptr_t)&AsB[wave * 512 + q * 2048], 16, 0, 0);
        }
#pragma unroll
        for (int q = 0; q < 4; ++q) {
            int c   = tid + q * 256;
            int o   = c >> 3;
            int csw = (c & 7) ^ (o & 7);
            const unsigned short* src = Bt + (size_t)o * KTOT + kc * 64 + csw * 8;
            __builtin_amdgcn_global_load_lds((gptr_t)src,
                (lptr_t)&BsB[wave * 512 + q * 2048], 16, 0, 0);
        }
        __syncthreads();
#pragma unroll
        for (int ks = 0; ks < 2; ++ks) {
            int kslot = ks * 4 + lhi;
            short8 a[2], b[4];
#pragma unroll
            for (int mi = 0; mi < 2; ++mi) {
                int row = wr * 32 + mi * 16 + l15;
                a[mi] = *(const short8*)&AsB[row * 64 + ((kslot ^ (row & 7)) << 3)];
            }
#pragma unroll
            for (int ni = 0; ni < 4; ++ni) {
                int o = wc * 64 + ni * 16 + l15;
                b[ni] = *(const short8*)&BsB[o * 64 + ((kslot ^ (o & 7)) << 3)];
            }
#pragma unroll
            for (int mi = 0; mi < 2; ++mi)
#pragma unroll
                for (int ni = 0; ni < 4; ++ni)
                    acc[mi][ni] = __builtin_amdgcn_mfma_f32_16x16x32_bf16(
                        a[mi], b[ni], acc[mi][ni], 0, 0, 0);
        }
        __syncthreads();
    }

#pragma unroll
    for (int mi = 0; mi < 2; ++mi) {
        int rowbase = brow + wr * 32 + mi * 16 + lhi * 4;
#pragma unroll
        for (int j = 0; j < 4; ++j) {
            int row = rowbase + j;
            if (row >= NND) continue;
            const float* as = asum + (size_t)row * NREL;
            float4 sa = *(const float4*)as;
            float4 sb = *(const float4*)(as + 4);
#pragma unroll
            for (int ni = 0; ni < 4; ++ni) {
                int col = wc * 64 + ni * 16 + l15;
                float v = acc[mi][ni][j] + bs[col];
                v += sa.x * br[0 * FDIM + col] + sa.y * br[1 * FDIM + col]
                   + sa.z * br[2 * FDIM + col] + sa.w * br[3 * FDIM + col];
                v += sb.x * br[4 * FDIM + col] + sb.y * br[5 * FDIM + col]
                   + sb.z * br[6 * FDIM + col] + sb.w * br[7 * FDIM + col];
                out[(size_t)row * FDIM + col] = v;
            }
        }
    }
}

extern "C" void kernel_launch(void* const* d_in, const int* in_sizes, int n_in,
                              void* d_out, int out_size, void* d_ws, size_t ws_size,
                              hipStream_t stream) {
    const float* x  = (const float*)d_in[0];
    const int*   ei = (const int*)d_in[1];
    const int*   et = (const int*)d_in[2];
    const float* Wr = (const float*)d_in[3];
    const float* br = (const float*)d_in[4];
    const float* Ws = (const float*)d_in[5];
    const float* bs = (const float*)d_in[6];
    const float* wa = (const float*)d_in[7];
    const float* ba = (const float*)d_in[8];
    float* out = (float*)d_out;
    float* ws  = (float*)d_ws;

    // workspace layout (float units; all offsets even -> 8B alignment for sorted2)
    const size_t abigF = ((size_t)MPAD * KTOT) / 2;
    const size_t btF   = ((size_t)FDIM * KTOT) / 2;
    const size_t xbF   = ((size_t)NND * FDIM) / 2;
    size_t o = 0;
    unsigned short* Abig = (unsigned short*)(ws + o); o += abigF;
    unsigned short* Bt   = (unsigned short*)(ws + o); o += btF;
    unsigned short* xb   = (unsigned short*)(ws + o); o += xbF;
    float* asum  = ws + o; o += (size_t)NND * NREL;
    float* a_src = ws + o; o += NND;
    float* a_tgt = ws + o; o += NND;
    int*   counts = (int*)(ws + o); o += NND;
    int*   offs   = (int*)(ws + o); o += NND;
    int*   bsum   = (int*)(ws + o); o += 64;
    unsigned long long* sorted2 = (unsigned long long*)(ws + o); o += 2 * (size_t)NED;
    if (ws_size < o * sizeof(float)) return;

    dim3 blk(256);
    const int nblk1024 = (NND + 1023) / 1024;

    hipMemsetAsync(Abig + (size_t)NND * KTOT, 0, (size_t)(MPAD - NND) * KTOT * 2, stream);
    hipMemsetAsync(counts, 0, NND * sizeof(int), stream);

    node_dots_kernel<<<(NND + 3) / 4, blk, 0, stream>>>(x, wa, a_src, a_tgt, Abig, xb);
    prep_bt_kernel<<<(FDIM * KTOT + 255) / 256, blk, 0, stream>>>(Ws, Wr, Bt);
    hist_kernel<<<(NED + 255) / 256, blk, 0, stream>>>(ei, counts);
    scan_pass1<<<nblk1024, 1024, 0, stream>>>(counts, offs, bsum, NND);
    scan_pass2<<<1, 64, 0, stream>>>(bsum, nblk1024);
    scan_pass3<<<nblk1024, 1024, 0, stream>>>(offs, bsum, NND);
    scatter_kernel<<<(NED + 255) / 256, blk, 0, stream>>>(ei, et, a_src, a_tgt, ba, offs, sorted2);
    segsum_kernel<<<(NND + 3) / 4, blk, 0, stream>>>(offs, sorted2, xb, Abig, asum);
    mfma_gemm_kernel<<<MPAD / 64, blk, 0, stream>>>(Abig, Bt, asum, br, bs, out);
}